// Round 5
// baseline (347.395 us; speedup 1.0000x reference)
//
#include <hip/hip_runtime.h>

// B=16, C=512, N=4096 (64x64), CP=64.
// out = gamma*(wo@softmax((wk x)(wq x)^T)@(wv x)+bo)+x
// 4-kernel bf16-MFMA pipeline:
//   k_prep:   one-shot fp32->bf16 of wq|wk|wv (fused [192][512]) and wo [512][64]
//   k_qkve:   reads x ONCE (2-deep reg-pipelined LDS transpose, per-chunk dbuf).
//             Computes q,k,v tiles; q,k NEVER leave the block: redistributed via
//             LDS (row-XOR swizzle) and contracted over n -> energy partial
//             epart[b][nb] (64 splits). v -> vt[b][n][cp] global.
//   k_softmax: sum 64 partials + rowwise softmax -> attn bf16
//   k_avout:  attn*V (avl in LDS, swizzled) + wo-proj + bias + gamma + residual

#define NN 4096
#define CIN 512
#define CPD 64

typedef short s8v __attribute__((ext_vector_type(8)));
typedef float f4v __attribute__((ext_vector_type(4)));
typedef unsigned short u16;

__device__ __forceinline__ u16 f2bf(float f) {
    union { float f; unsigned int u; } c; c.f = f;
    unsigned int r = c.u + 0x7FFFu + ((c.u >> 16) & 1u);   // RNE
    return (u16)(r >> 16);
}

union PK { uint2 u[2]; s8v v; };

// ---------------- K0: one-shot weight convert. 128 blocks x 256 thr, 4 elems/thr.
__global__ __launch_bounds__(256) void k_prep(
    const float* __restrict__ wq, const float* __restrict__ wk,
    const float* __restrict__ wv, const float* __restrict__ wo,
    u16* __restrict__ wqkvb, u16* __restrict__ wob)
{
    const int t = blockIdx.x * 256 + threadIdx.x;   // 32768 threads
    const int i4 = t * 4;
    const float* src; u16* dst; int off;
    if (i4 < 98304) {                // 3 * 64*512
        const int r = i4 >> 15;
        src = (r == 0) ? wq : (r == 1) ? wk : wv;
        off = i4 & 32767;
        dst = wqkvb + (r << 15);
    } else {
        src = wo; off = i4 - 98304; dst = wob;
    }
    float4 v = *(const float4*)(src + off);
    u16 tmp[4] = { f2bf(v.x), f2bf(v.y), f2bf(v.z), f2bf(v.w) };
    *(uint2*)(dst + off) = *(const uint2*)tmp;
}

// ---------------- K1: QKV + energy partial. grid (64 nb, 16 b), block 256
// (4 waves). Block tile: 192 proj rows x 64 n-cols, K = 512 in 8 chunks of 64.
// 2-deep register pipeline: loads for chunk cc+2 issued before compute of cc.
// LDS chunk layout: row n (0..63), 16 slots of 4 c; slot = c4 ^ (n&15).
// After the c-loop: q,k tiles -> LDS ([o][n], col ^ (row&7)*8 swizzle), then
// E[i][j] += sum_n k[i][n] q[j][n] for this n-slice -> epart[b][nb].
__global__ __launch_bounds__(256, 4) void k_qkve(
    const float* __restrict__ x, const u16* __restrict__ wqkvb,
    const float* __restrict__ bq, const float* __restrict__ bk,
    const float* __restrict__ bv,
    u16* __restrict__ vt, float* __restrict__ epart)
{
    const int nb = blockIdx.x, b = blockIdx.y;
    const int t = threadIdx.x;
    const int w = t >> 6, L = t & 63, quad = L >> 4, l15 = L & 15;
    const int n0 = nb * 64;

    __shared__ u16 xs[2][64 * 64];   // dbuf staging; later aliased as q/k tiles

    const int nl = t & 63, c4b = t >> 6;
    const float* xp = x + (size_t)b * CIN * NN + n0 + nl;

    f4v acc[3][4];   // [p][nn]
    #pragma unroll
    for (int p = 0; p < 3; ++p)
        #pragma unroll
        for (int nn = 0; nn < 4; ++nn) acc[p][nn] = (f4v){0.f,0.f,0.f,0.f};

    const u16* wb = wqkvb + (size_t)(w * 16 + l15) * CIN;

    float xrA[16], xrB[16];

    auto issue = [&](int cc, float* xr) {
        const int c0n = cc * 64;
        #pragma unroll
        for (int i = 0; i < 4; ++i)
            #pragma unroll
            for (int j = 0; j < 4; ++j)
                xr[i * 4 + j] = xp[(size_t)(c0n + (c4b + 4 * i) * 4 + j) * NN];
    };
    auto stage = [&](const float* xr, u16* dst) {
        #pragma unroll
        for (int i = 0; i < 4; ++i) {
            u16 t4[4];
            #pragma unroll
            for (int j = 0; j < 4; ++j) t4[j] = f2bf(xr[i * 4 + j]);
            const int slot = (c4b + 4 * i) ^ (nl & 15);
            *(uint2*)&dst[nl * 64 + slot * 4] = *(const uint2*)t4;
        }
    };
    auto compute = [&](int cc, const u16* src) {
        #pragma unroll
        for (int ks2 = 0; ks2 < 2; ++ks2) {
            s8v bf[4];
            #pragma unroll
            for (int nn = 0; nn < 4; ++nn) {
                const int row = nn * 16 + l15;
                const int sb = ks2 * 8 + quad * 2;
                PK p_;
                p_.u[0] = *(const uint2*)&src[row * 64 + ((sb ^ l15) * 4)];
                p_.u[1] = *(const uint2*)&src[row * 64 + (((sb + 1) ^ l15) * 4)];
                bf[nn] = p_.v;
            }
            const int cgl = cc * 64 + ks2 * 32 + quad * 8;
            #pragma unroll
            for (int p = 0; p < 3; ++p) {
                s8v af = *(const s8v*)(wb + (size_t)p * 64 * CIN + cgl);
                #pragma unroll
                for (int nn = 0; nn < 4; ++nn)
                    acc[p][nn] = __builtin_amdgcn_mfma_f32_16x16x32_bf16(
                        af, bf[nn], acc[p][nn], 0, 0, 0);
            }
        }
    };

    // prologue: chunks 0,1 in flight; chunk 0 staged
    issue(0, xrA);
    issue(1, xrB);
    stage(xrA, xs[0]);
    __syncthreads();

    #pragma unroll
    for (int cb2 = 0; cb2 < 4; ++cb2) {
        const int cc = cb2 * 2;
        if (cc + 2 < 8) issue(cc + 2, xrA);     // 2 chunks ahead
        compute(cc, xs[0]);
        stage(xrB, xs[1]);                      // chunk cc+1 (landed)
        __syncthreads();
        if (cc + 3 < 8) issue(cc + 3, xrB);
        compute(cc + 1, xs[1]);
        if (cc + 2 < 8) stage(xrA, xs[0]);
        __syncthreads();
    }

    const int orow = w * 16 + quad * 4;

    // v epilogue: vt[b][n][o] bf16
    {
        float4 v4 = *(const float4*)(bv + orow);
        const float vb_[4] = { v4.x, v4.y, v4.z, v4.w };
        u16* vtb = vt + (size_t)b * NN * CPD;
        #pragma unroll
        for (int nn = 0; nn < 4; ++nn) {
            const int n = n0 + nn * 16 + l15;
            u16 tmp[4];
            #pragma unroll
            for (int r = 0; r < 4; ++r) tmp[r] = f2bf(acc[2][nn][r] + vb_[r]);
            *(uint2*)(vt + (size_t)b * NN * CPD + (size_t)n * CPD + orow) =
                *(const uint2*)tmp;
            (void)vtb;
        }
    }

    // q,k tiles -> LDS (aliasing xs; safe: loop ended with barrier)
    u16* q_l = &xs[0][0];   // [64][64], col ^ ((row&7)*8)
    u16* k_l = &xs[1][0];
    {
        float4 q4 = *(const float4*)(bq + orow);
        float4 k4 = *(const float4*)(bk + orow);
        const float qb_[4] = { q4.x, q4.y, q4.z, q4.w };
        const float kb_[4] = { k4.x, k4.y, k4.z, k4.w };
        #pragma unroll
        for (int nn = 0; nn < 4; ++nn) {
            const int col = nn * 16 + l15;
            #pragma unroll
            for (int r = 0; r < 4; ++r) {
                const int row = orow + r;
                const int cs = col ^ ((row & 7) * 8);
                q_l[row * 64 + cs] = f2bf(acc[0][nn][r] + qb_[r]);
                k_l[row * 64 + cs] = f2bf(acc[1][nn][r] + kb_[r]);
            }
        }
    }
    __syncthreads();

    // E-partial: wave w owns rows i = w*16..+15, all 64 j. Contraction over 64 n.
    {
        f4v acc_e[4];
        #pragma unroll
        for (int jt = 0; jt < 4; ++jt) acc_e[jt] = (f4v){0.f,0.f,0.f,0.f};
        #pragma unroll
        for (int ks = 0; ks < 2; ++ks) {
            const int nsl = ks * 32 + quad * 8;
            const int arow = w * 16 + l15;
            s8v afk = *(const s8v*)&k_l[arow * 64 + (nsl ^ ((arow & 7) * 8))];
            #pragma unroll
            for (int jt = 0; jt < 4; ++jt) {
                const int brow = jt * 16 + l15;
                s8v bfq = *(const s8v*)&q_l[brow * 64 + (nsl ^ ((brow & 7) * 8))];
                acc_e[jt] = __builtin_amdgcn_mfma_f32_16x16x32_bf16(
                    afk, bfq, acc_e[jt], 0, 0, 0);
            }
        }
        float* ep = epart + ((size_t)b * 64 + nb) * 4096;
        #pragma unroll
        for (int jt = 0; jt < 4; ++jt)
            #pragma unroll
            for (int r = 0; r < 4; ++r)
                ep[(w * 16 + quad * 4 + r) * 64 + jt * 16 + l15] = acc_e[jt][r];
    }
}

// ---------------- K2: sum 64 partials + softmax over j -> attn bf16 [b][i][j]
__global__ __launch_bounds__(64) void k_softmax(
    const float* __restrict__ epart, u16* __restrict__ attn)
{
    const int i = blockIdx.x;
    const int b = blockIdx.y;
    const int j = threadIdx.x;
    float s = 0.f;
    #pragma unroll
    for (int sp = 0; sp < 64; ++sp)
        s += epart[((size_t)b * 64 + sp) * 4096 + i * 64 + j];
    float m = s;
    #pragma unroll
    for (int off = 32; off; off >>= 1) m = fmaxf(m, __shfl_xor(m, off));
    float e = __expf(s - m);
    float tot = e;
    #pragma unroll
    for (int off = 32; off; off >>= 1) tot += __shfl_xor(tot, off);
    attn[(size_t)b * 4096 + i * 64 + j] = f2bf(e / tot);
}

// ---------------- K3: fused attn*V + out-proj + residual.
// grid (64 nb, 16 b), block 256 (4 waves, each 16 n). n-tile 64, 8 KB LDS.
// phase1: D1[i][n] = attn x vt -> avl LDS [n][i] (c4-slot XOR swizzle).
// phase2: D2[n][c] = avl x wob (global B-frags), x-residual prefetched early.
__global__ __launch_bounds__(256, 4) void k_avout(
    const u16* __restrict__ vt, const u16* __restrict__ attn,
    const u16* __restrict__ wob, const float* __restrict__ bo,
    const float* __restrict__ gamma, const float* __restrict__ x,
    float* __restrict__ out)
{
    const int nb = blockIdx.x, b = blockIdx.y;
    const int t = threadIdx.x;
    const int wv_ = t >> 6, L = t & 63, quad = L >> 4, l15 = L & 15;
    const int n0 = nb * 64;

    __shared__ u16 avl[64 * 64];   // [n][i], slot-swizzled, 8 KB

    // phase 1: D1[i 0..63][n-local: wave covers wv_*16 + l15]
    {
        const u16* ab  = attn + (size_t)b * 4096;
        const u16* vtb = vt + (size_t)b * NN * CPD;
        f4v acc1[4];
        #pragma unroll
        for (int a = 0; a < 4; ++a) acc1[a] = (f4v){0.f,0.f,0.f,0.f};
        const int nloc = wv_ * 16 + l15;
        #pragma unroll
        for (int ks = 0; ks < 2; ++ks) {
            const int j = ks * 32 + quad * 8;
            s8v bfv = *(const s8v*)(vtb + (size_t)(n0 + nloc) * CPD + j);
            #pragma unroll
            for (int it = 0; it < 4; ++it) {
                s8v af = *(const s8v*)(ab + (size_t)(it * 16 + l15) * 64 + j);
                acc1[it] = __builtin_amdgcn_mfma_f32_16x16x32_bf16(
                    af, bfv, acc1[it], 0, 0, 0);
            }
        }
        // lane holds D1[i = it*16+quad*4+r][n-local = nloc]; write avl[n][i]
        #pragma unroll
        for (int it = 0; it < 4; ++it) {
            u16 t4[4];
            #pragma unroll
            for (int r = 0; r < 4; ++r) t4[r] = f2bf(acc1[it][r]);
            const int slot = (it * 4 + quad) ^ l15;
            *(uint2*)&avl[nloc * 64 + slot * 4] = *(const uint2*)t4;
        }
    }
    __syncthreads();

    // phase 2: out = gamma*(wo@av + bo) + x, float4 along n
    const float g = gamma[0];
    for (int cb = 0; cb < 8; ++cb) {
        // prefetch x residuals for this cb (independent of MFMA below)
        float4 xr4[4];
        size_t idx4[4];
        #pragma unroll
        for (int ct = 0; ct < 4; ++ct) {
            const int c = cb * 64 + ct * 16 + l15;
            const int nb4 = n0 + wv_ * 16 + quad * 4;
            idx4[ct] = ((size_t)b * CIN + c) * NN + nb4;
            xr4[ct] = *(const float4*)(x + idx4[ct]);
        }
        f4v acc2[4];   // [ct]
        #pragma unroll
        for (int a = 0; a < 4; ++a) acc2[a] = (f4v){0.f,0.f,0.f,0.f};
        #pragma unroll
        for (int ks = 0; ks < 2; ++ks) {
            const int sb = ks * 8 + quad * 2;
            PK p_;
            p_.u[0] = *(const uint2*)&avl[(wv_ * 16 + l15) * 64 + ((sb ^ l15) * 4)];
            p_.u[1] = *(const uint2*)&avl[(wv_ * 16 + l15) * 64 + (((sb + 1) ^ l15) * 4)];
            const s8v af2 = p_.v;
            const int i0 = ks * 32 + quad * 8;
            #pragma unroll
            for (int ct = 0; ct < 4; ++ct) {
                s8v bf2 = *(const s8v*)(wob +
                    (size_t)(cb * 64 + ct * 16 + l15) * CPD + i0);
                acc2[ct] = __builtin_amdgcn_mfma_f32_16x16x32_bf16(
                    af2, bf2, acc2[ct], 0, 0, 0);
            }
        }
        #pragma unroll
        for (int ct = 0; ct < 4; ++ct) {
            const float bs = bo[cb * 64 + ct * 16 + l15];
            float4 r4;
            r4.x = g * (acc2[ct][0] + bs) + xr4[ct].x;
            r4.y = g * (acc2[ct][1] + bs) + xr4[ct].y;
            r4.z = g * (acc2[ct][2] + bs) + xr4[ct].z;
            r4.w = g * (acc2[ct][3] + bs) + xr4[ct].w;
            *(float4*)(out + idx4[ct]) = r4;
        }
    }
}

extern "C" void kernel_launch(void* const* d_in, const int* in_sizes, int n_in,
                              void* d_out, int out_size, void* d_ws, size_t ws_size,
                              hipStream_t stream) {
    const float* x  = (const float*)d_in[0];
    const float* wq = (const float*)d_in[1];
    const float* bq = (const float*)d_in[2];
    const float* wk = (const float*)d_in[3];
    const float* bk = (const float*)d_in[4];
    const float* wv = (const float*)d_in[5];
    const float* bv = (const float*)d_in[6];
    const float* wo = (const float*)d_in[7];
    const float* bo = (const float*)d_in[8];
    const float* gm = (const float*)d_in[9];
    float* out = (float*)d_out;

    // workspace (bytes), total ~24.4 MB:
    char* wsb = (char*)d_ws;
    u16*   vt    = (u16*)wsb;                         //  8.39 MB [b][n][cp]
    float* epart = (float*)(wsb + 8388608);           // 16.78 MB [b][64][64][64]
    u16*   attn  = (u16*)(wsb + 25165824);            //  0.13 MB [b][64][64]
    u16*   wqkvb = (u16*)(wsb + 25296896);            //  0.20 MB [192][512]
    u16*   wob   = (u16*)(wsb + 25493504);            //  0.06 MB [512][64]

    k_prep<<<128, 256, 0, stream>>>(wq, wk, wv, wo, wqkvb, wob);
    k_qkve<<<dim3(64, 16), 256, 0, stream>>>(x, wqkvb, bq, bk, bv, vt, epart);
    k_softmax<<<dim3(64, 16), 64, 0, stream>>>(epart, attn);
    k_avout<<<dim3(64, 16), 256, 0, stream>>>(vt, attn, wob, bo, gm, x, out);
}